// Round 1
// baseline (682.679 us; speedup 1.0000x reference)
//
#include <hip/hip_runtime.h>

typedef __bf16 bf16x8 __attribute__((ext_vector_type(8)));
typedef __bf16 bf16x4 __attribute__((ext_vector_type(4)));
typedef float  f32x4  __attribute__((ext_vector_type(4)));
typedef float  f32x16 __attribute__((ext_vector_type(16)));

#define MFMA16(A, B, C) __builtin_amdgcn_mfma_f32_16x16x32_bf16(A, B, C, 0, 0, 0)
#define MFMA32(A, B, C) __builtin_amdgcn_mfma_f32_32x32x16_bf16(A, B, C, 0, 0, 0)

#if __has_builtin(__builtin_amdgcn_exp2f)
#define EXP2F(x) __builtin_amdgcn_exp2f(x)
#else
#define EXP2F(x) exp2f(x)
#endif

__device__ __forceinline__ unsigned pk_bf16(float lo, float hi) {
    union { __bf16 b[2]; unsigned u; } r;
    r.b[0] = (__bf16)lo; r.b[1] = (__bf16)hi;
    return r.u;
}

// ---------------- elementwise fp32 -> bf16 ----------------
__global__ __launch_bounds__(256) void convert_f32_bf16(const float* __restrict__ src,
                                                        __bf16* __restrict__ dst) {
    size_t i = ((size_t)blockIdx.x * 256 + threadIdx.x) * 4;
    float4 v = *(const float4*)(src + i);
    bf16x4 o;
    o.x = (__bf16)v.x; o.y = (__bf16)v.y; o.z = (__bf16)v.z; o.w = (__bf16)v.w;
    *(bf16x4*)(dst + i) = o;
}

// ---------------- 2048x2048 fp32 -> bf16 transpose (W -> W^T rows=[n][k]) ----------------
__global__ __launch_bounds__(256) void transpose_conv(const float* __restrict__ src,
                                                      __bf16* __restrict__ dst) {
    __shared__ float t[32][33];
    int x0 = blockIdx.x * 32, y0 = blockIdx.y * 32;
    int tx = threadIdx.x, ty = threadIdx.y;   // 32x8
    for (int r = 0; r < 4; ++r)
        t[ty + 8 * r][tx] = src[(size_t)(y0 + ty + 8 * r) * 2048 + x0 + tx];
    __syncthreads();
    for (int r = 0; r < 4; ++r)
        dst[(size_t)(x0 + ty + 8 * r) * 2048 + y0 + tx] = (__bf16)t[tx][ty + 8 * r];
}

// ---------------- per-head V transpose: qkv[s][4096+h*128+d] -> vtb[h][d][s] ----------------
__global__ __launch_bounds__(256) void v_transpose(const __bf16* __restrict__ qkv,
                                                   __bf16* __restrict__ vtb) {
    __shared__ __bf16 t[32][33];
    int h = blockIdx.z;
    int s0 = blockIdx.x * 32, d0 = blockIdx.y * 32;
    int tx = threadIdx.x, ty = threadIdx.y;   // 32x8
    for (int r = 0; r < 4; ++r)
        t[ty + 8 * r][tx] = qkv[(size_t)(s0 + ty + 8 * r) * 6144 + 4096 + h * 128 + d0 + tx];
    __syncthreads();
    for (int r = 0; r < 4; ++r)
        vtb[(size_t)h * 128 * 4096 + (size_t)(d0 + ty + 8 * r) * 4096 + s0 + tx] = t[tx][ty + 8 * r];
}

// ---------------- fused RMSNorm + RoPE; head-major Q (pre-scaled by log2e/sqrt(128)) and K ----------------
__global__ __launch_bounds__(64) void rmsrope(const __bf16* __restrict__ qkv,
                                              const float* __restrict__ qw,
                                              const float* __restrict__ kw,
                                              const int* __restrict__ pos_ids,
                                              __bf16* __restrict__ qhb,
                                              __bf16* __restrict__ khb) {
    int s = blockIdx.x;
    int slot = blockIdx.y;              // 0..31: 0-15 = q heads, 16-31 = k heads
    int lane = threadIdx.x;             // 0..63, handles dim pair (2*lane, 2*lane+1)
    bool isQ = slot < 16;
    int h = slot & 15;
    size_t base = (size_t)s * 6144 + (isQ ? 0 : 2048) + h * 128 + lane * 2;
    float x0 = (float)qkv[base], x1 = (float)qkv[base + 1];
    float ss = x0 * x0 + x1 * x1;
    for (int m = 1; m < 64; m <<= 1) ss += __shfl_xor(ss, m);
    float rr = rsqrtf(ss * (1.0f / 128.0f) + 1e-6f);
    const float* wp = isQ ? qw : kw;
    float n0 = x0 * rr * wp[lane * 2], n1 = x1 * rr * wp[lane * 2 + 1];
    float freq = powf(10000.0f, -(float)lane * (1.0f / 64.0f));
    float ang = (float)pos_ids[s] * freq;
    float sn, cs;
    sincosf(ang, &sn, &cs);
    float o0 = n0 * cs - n1 * sn;
    float o1 = n0 * sn + n1 * cs;
    // fold (1/sqrt(128)) * log2(e) into Q so scores are in exp2 domain
    if (isQ) { o0 *= 0.12751744416196178f; o1 *= 0.12751744416196178f; }
    __bf16* dst = (isQ ? qhb : khb) + (size_t)h * 4096 * 128 + (size_t)s * 128 + lane * 2;
    dst[0] = (__bf16)o0; dst[1] = (__bf16)o1;
}

// ---------------- generic bf16 MFMA GEMM: C[M,N] = A[M,K] * Bt[N,K]^T ----------------
// 128x128 tile, 4 waves, 4x4 16x16x32 MFMA per wave. global_load_lds width-16 staging (m97).
template <bool F32OUT>
__global__ __launch_bounds__(256) void gemm_bt(const __bf16* __restrict__ A, int lda,
                                               const __bf16* __restrict__ Bt, int ldb,
                                               void* __restrict__ Cout, int ldc, int K) {
    __shared__ __bf16 as[128][32];   // unpadded: required by global_load_lds contiguity
    __shared__ __bf16 bs[128][32];
    const int m0 = blockIdx.x * 128, n0 = blockIdx.y * 128;
    const int t = threadIdx.x;
    const int lane = t & 63, w = t >> 6;
    const int wm = (w >> 1) * 64, wn = (w & 1) * 64;
    const int ln = lane & 15, quad = lane >> 4;
    auto as3 = (__attribute__((address_space(3))) uint32_t*)as;
    auto bs3 = (__attribute__((address_space(3))) uint32_t*)bs;
    f32x4 acc[4][4] = {};
    for (int k0 = 0; k0 < K; k0 += 32) {
        for (int c = 0; c < 2; ++c) {
            int g = c * 256 + t;               // chunk id: 512 chunks of 16B per tile
            int row = g >> 2, kc = g & 3;
            const __bf16* ga = &A[(size_t)(m0 + row) * lda + k0 + kc * 8];
            const __bf16* gb = &Bt[(size_t)(n0 + row) * ldb + k0 + kc * 8];
            __builtin_amdgcn_global_load_lds((const __attribute__((address_space(1))) uint32_t*)ga,
                                             as3 + c * 1024 + w * 256, 16, 0, 0);
            __builtin_amdgcn_global_load_lds((const __attribute__((address_space(1))) uint32_t*)gb,
                                             bs3 + c * 1024 + w * 256, 16, 0, 0);
        }
        __syncthreads();
        bf16x8 af[4], bfr[4];
        for (int i = 0; i < 4; ++i) af[i] = *(const bf16x8*)&as[wm + i * 16 + ln][quad * 8];
        for (int j = 0; j < 4; ++j) bfr[j] = *(const bf16x8*)&bs[wn + j * 16 + ln][quad * 8];
        for (int i = 0; i < 4; ++i)
            for (int j = 0; j < 4; ++j)
                acc[i][j] = MFMA16(af[i], bfr[j], acc[i][j]);
        __syncthreads();
    }
    // C/D layout: col = lane&15, row = quad*4 + r   [m89/m91 verified]
    for (int i = 0; i < 4; ++i)
        for (int j = 0; j < 4; ++j)
            for (int r = 0; r < 4; ++r) {
                int row = m0 + wm + i * 16 + quad * 4 + r;
                int col = n0 + wn + j * 16 + ln;
                if (F32OUT) ((float*)Cout)[(size_t)row * ldc + col] = acc[i][j][r];
                else        ((__bf16*)Cout)[(size_t)row * ldc + col] = (__bf16)acc[i][j][r];
            }
}

// ---------------- flash attention, 32x32 MFMA, in-register softmax ----------------
// Fixed-max softmax: q/k are RMS-normalized so |s*log2e| <= sqrt(128)*log2e = 16.33 < 16.5.
// p = exp2(s~ - 16.5) is exact softmax after final division; no running max/rescale.
// Swapped QK^T (S^T = K*Q^T): lane's col = its own q row -> P stays in registers;
// P->bf16 A-frags via cvt_pk + permlane32_swap (T12, m214 recipe). ks/vs XOR-swizzled (T2).
__global__ __launch_bounds__(256, 2) void flash_attn(const __bf16* __restrict__ Q,
                                                     const __bf16* __restrict__ Kb,
                                                     const __bf16* __restrict__ Vt,
                                                     __bf16* __restrict__ ctx) {
    __shared__ __bf16 ks[64][128];   // keys x dim, XOR-swizzled 16B chunks
    __shared__ __bf16 vs[128][64];   // dim x keys, XOR-swizzled 16B chunks
    __shared__ float lred[4][32];    // per-wave row-sum broadcast

    // T1: XCD-contiguous remap; each XCD's 64 blocks cover 2 heads (K/V = 4MB = one L2)
    int bid = blockIdx.x + (int)gridDim.x * blockIdx.y;   // 512 blocks
    int swz = (bid & 7) * 64 + (bid >> 3);
    const int h  = swz >> 5;
    const int m0 = (swz & 31) * 128;

    const int t = threadIdx.x;
    const int lane = t & 63, w = t >> 6;
    const int q32 = lane & 31, hi = lane >> 5;

    const __bf16* Qh = Q  + (size_t)h * 4096 * 128;
    const __bf16* Kh = Kb + (size_t)h * 4096 * 128;
    const __bf16* Vh = Vt + (size_t)h * 128 * 4096;

    char* ksb = (char*)&ks[0][0];
    char* vsb = (char*)&vs[0][0];

    // ---- stage Q through ks (two 64-row halves), keep 8 B-frags in registers ----
    // B-frag (32x32x16): lane holds Q[q = w*32 + (lane&31)][d = dc*16 + hi*8 + 0..7]
    bf16x8 qf[8];
    for (int half = 0; half < 2; ++half) {
        for (int i = 0; i < 4; ++i) {
            int chunk = t + i * 256;
            int row = chunk >> 4, cc = chunk & 15;
            uint4 v = *(const uint4*)&Qh[(size_t)(m0 + half * 64 + row) * 128 + cc * 8];
            *(uint4*)(ksb + row * 256 + ((cc ^ (row & 7)) << 4)) = v;
        }
        __syncthreads();
        if ((w >> 1) == half) {
            int r = (w & 1) * 32 + q32;
            for (int dc = 0; dc < 8; ++dc)
                qf[dc] = *(const bf16x8*)(ksb + r * 256 + ((((dc << 1) | hi) ^ (r & 7)) << 4));
        }
        __syncthreads();
    }

    // ---- prologue: prefetch tile 0 into registers (T14 async-stage split) ----
    uint4 kst[4], vst[4];
    for (int i = 0; i < 4; ++i) {
        int chunk = t + i * 256;
        int krow = chunk >> 4, kc = chunk & 15;
        kst[i] = *(const uint4*)&Kh[(size_t)krow * 128 + kc * 8];
        int vrow = chunk >> 3, vc = chunk & 7;
        vst[i] = *(const uint4*)&Vh[(size_t)vrow * 4096 + vc * 8];
    }

    f32x16 oacc[4] = {};
    float rs = 0.0f;

    for (int kb = 0; kb < 64; ++kb) {
        __syncthreads();
        for (int i = 0; i < 4; ++i) {        // write staged tile to LDS (swizzled)
            int chunk = t + i * 256;
            int krow = chunk >> 4, kc = chunk & 15;
            *(uint4*)(ksb + krow * 256 + ((kc ^ (krow & 7)) << 4)) = kst[i];
            int vrow = chunk >> 3, vc = chunk & 7;
            *(uint4*)(vsb + vrow * 128 + ((vc ^ (vrow & 7)) << 4)) = vst[i];
        }
        __syncthreads();
        if (kb + 1 < 64) {                   // issue next tile's loads; land under compute
            for (int i = 0; i < 4; ++i) {
                int chunk = t + i * 256;
                int krow = chunk >> 4, kc = chunk & 15;
                kst[i] = *(const uint4*)&Kh[(size_t)(kb * 64 + 64 + krow) * 128 + kc * 8];
                int vrow = chunk >> 3, vc = chunk & 7;
                vst[i] = *(const uint4*)&Vh[(size_t)vrow * 4096 + kb * 64 + 64 + vc * 8];
            }
        }

        // ---- S^T = K * Q^T - 16.5 (bias via MFMA C-init) ----
        // A-frag = K: lane holds K[k = kt*32 + (lane&31)][d = dc*16 + hi*8 + 0..7]
        f32x16 sacc[2];
        for (int e = 0; e < 16; ++e) { sacc[0][e] = -16.5f; sacc[1][e] = -16.5f; }
        __builtin_amdgcn_s_setprio(1);
        for (int dc = 0; dc < 8; ++dc) {
            int co = (dc << 1) | hi;
            bf16x8 kf0 = *(const bf16x8*)(ksb + q32 * 256        + ((co ^ (q32 & 7)) << 4));
            bf16x8 kf1 = *(const bf16x8*)(ksb + (32 + q32) * 256 + ((co ^ (q32 & 7)) << 4));
            sacc[0] = MFMA32(kf0, qf[dc], sacc[0]);
            sacc[1] = MFMA32(kf1, qf[dc], sacc[1]);
        }
        __builtin_amdgcn_s_setprio(0);

        // ---- per 32-key tile: exp2, in-register P->bf16 A-frags, PV ----
        // S^T layout: lane holds P[q = lane&31][k_local = (r&3) + 8*(r>>2) + 4*hi]
        for (int kt = 0; kt < 2; ++kt) {
            float p[16];
            for (int r = 0; r < 16; ++r) { p[r] = EXP2F(sacc[kt][r]); rs += p[r]; }
            // A-frag chunk c (k in [16c,16c+16)): lane needs k = 16c + 8*hi + {0..7}
            // regs [8c..8c+8): k = 16c + 4hi + {0..3} and 16c + 8 + 4hi + {0..3}
            bf16x8 pf[2];
            for (int c = 0; c < 2; ++c) {
                int b = c * 8;
                unsigned a0 = pk_bf16(p[b + 0], p[b + 1]);
                unsigned a1 = pk_bf16(p[b + 2], p[b + 3]);
                unsigned b0 = pk_bf16(p[b + 4], p[b + 5]);
                unsigned b1 = pk_bf16(p[b + 6], p[b + 7]);
                auto s0 = __builtin_amdgcn_permlane32_swap(a0, b0, false, false);
                auto s1 = __builtin_amdgcn_permlane32_swap(a1, b1, false, false);
                union { unsigned u[4]; bf16x8 v; } pu;
                pu.u[0] = s0[0]; pu.u[1] = s1[0]; pu.u[2] = s0[1]; pu.u[3] = s1[1];
                pf[c] = pu.v;
            }
            // B-frag = V: lane holds V[k][d = dt*32 + (lane&31)] from V^T rows, 8 contiguous k
            __builtin_amdgcn_s_setprio(1);
            for (int dt = 0; dt < 4; ++dt) {
                int vrow = dt * 32 + q32;
                for (int c = 0; c < 2; ++c) {
                    int co = ((kt * 2 + c) << 1) | hi;
                    bf16x8 vf = *(const bf16x8*)(vsb + vrow * 128 + ((co ^ (vrow & 7)) << 4));
                    oacc[dt] = MFMA32(pf[c], vf, oacc[dt]);
                }
            }
            __builtin_amdgcn_s_setprio(0);
        }
    }

    // ---- epilogue: full row-sum (lane + partner lane^32), broadcast, divide, store ----
    float rt = rs + __shfl_xor(rs, 32);
    if (hi == 0) lred[w][q32] = rt;
    __syncthreads();
    float inv[16];
    for (int r = 0; r < 16; ++r)
        inv[r] = 1.0f / lred[w][(r & 3) + 8 * (r >> 2) + 4 * hi];
    // O layout (32x32 D): col = lane&31 = d, row = (r&3) + 8*(r>>2) + 4*hi = q_local
    for (int dt = 0; dt < 4; ++dt)
        for (int r = 0; r < 16; ++r) {
            int row = m0 + w * 32 + (r & 3) + 8 * (r >> 2) + 4 * hi;
            int col = h * 128 + dt * 32 + q32;
            ctx[(size_t)row * 2048 + col] = (__bf16)(oacc[dt][r] * inv[r]);
        }
}

// ---------------- launch ----------------
extern "C" void kernel_launch(void* const* d_in, const int* in_sizes, int n_in,
                              void* d_out, int out_size, void* d_ws, size_t ws_size,
                              hipStream_t stream) {
    const float* hs  = (const float*)d_in[0];
    const int*   pos = (const int*)d_in[1];
    const float* wq  = (const float*)d_in[2];
    const float* wk  = (const float*)d_in[3];
    const float* wv  = (const float*)d_in[4];
    const float* wo  = (const float*)d_in[5];
    const float* qw  = (const float*)d_in[6];
    const float* kw  = (const float*)d_in[7];

    char* ws = (char*)d_ws;
    const size_t MB = 1024 * 1024;
    __bf16* xb     = (__bf16*)(ws + 0);
    __bf16* wqkvtb = (__bf16*)(ws + 16 * MB);
    __bf16* qhb    = (__bf16*)(ws + 0);
    __bf16* khb    = (__bf16*)(ws + 16 * MB);
    __bf16* vtb    = (__bf16*)(ws + 32 * MB);
    __bf16* qkvb   = (__bf16*)(ws + 48 * MB);
    __bf16* ctxb   = (__bf16*)(ws + 48 * MB);
    __bf16* wotb   = (__bf16*)(ws + 96 * MB);

    dim3 tb(32, 8);
    convert_f32_bf16<<<8192, 256, 0, stream>>>(hs, xb);
    transpose_conv<<<dim3(64, 64), tb, 0, stream>>>(wq, wqkvtb);
    transpose_conv<<<dim3(64, 64), tb, 0, stream>>>(wk, wqkvtb + (size_t)2048 * 2048);
    transpose_conv<<<dim3(64, 64), tb, 0, stream>>>(wv, wqkvtb + (size_t)2 * 2048 * 2048);
    transpose_conv<<<dim3(64, 64), tb, 0, stream>>>(wo, wotb);

    // QKV projection: [4096,2048] x [2048,6144]
    gemm_bt<false><<<dim3(32, 48), 256, 0, stream>>>(xb, 2048, wqkvtb, 2048, qkvb, 6144, 2048);

    rmsrope<<<dim3(4096, 32), 64, 0, stream>>>(qkvb, qw, kw, pos, qhb, khb);
    v_transpose<<<dim3(128, 4, 16), tb, 0, stream>>>(qkvb, vtb);

    flash_attn<<<dim3(32, 16), 256, 0, stream>>>(qhb, khb, vtb, ctxb);

    // output projection: [4096,2048] x [2048,2048] -> fp32 out
    gemm_bt<true><<<dim3(32, 16), 256, 0, stream>>>(ctxb, 2048, wotb, 2048, d_out, 2048, 2048);
}